// Round 1
// baseline (1888.782 us; speedup 1.0000x reference)
//
#include <hip/hip_runtime.h>
#include <math.h>

// Problem constants (from setup_inputs): B=8, S=1024, D=256, H=8, hd=32, L=4, M=128
#define Bb 8
#define Ss 1024
#define Dd 256
#define Hh 8
#define HD 32
#define LL 4
#define MM 128
#define ROWS (Bb*Ss)      // 8192
#define D3 (3*Dd)         // 768

// ---------------------------------------------------------------------------
// Tiled fp32 GEMM: C[M,N] = A[M,K] @ W[K,N] + bias (+ residual) (+ relu)
// Tile 64x64, BK=16, 256 threads, 4x4 micro-tile per thread.
// ---------------------------------------------------------------------------
template<bool RELU, bool HAS_RES>
__global__ __launch_bounds__(256)
void gemm_k(const float* __restrict__ A, const float* __restrict__ W,
            const float* __restrict__ bias, const float* __restrict__ Rres,
            float* __restrict__ C, int Mm, int Nn, int Kk)
{
    __shared__ float As[16][64];   // [k][m]  (transposed store)
    __shared__ float Bs[16][64];   // [k][n]

    const int t  = threadIdx.x;
    const int tx = t & 15;         // 0..15  -> col group
    const int ty = t >> 4;         // 0..15  -> row group
    const int bn0 = blockIdx.x * 64;
    const int bm0 = blockIdx.y * 64;

    // load indices
    const int am = t >> 2;         // 0..63 row of A tile
    const int ak = (t & 3) * 4;    // 0,4,8,12
    const int bk = t >> 4;         // 0..15 row of W tile
    const int bn = (t & 15) * 4;   // 0..60

    float acc[4][4] = {};

    for (int k0 = 0; k0 < Kk; k0 += 16) {
        float4 av = *(const float4*)(A + (size_t)(bm0 + am) * Kk + k0 + ak);
        float4 bv = *(const float4*)(W + (size_t)(k0 + bk) * Nn + bn0 + bn);
        __syncthreads();   // previous iteration's reads complete
        As[ak + 0][am] = av.x;
        As[ak + 1][am] = av.y;
        As[ak + 2][am] = av.z;
        As[ak + 3][am] = av.w;
        *(float4*)&Bs[bk][bn] = bv;
        __syncthreads();
#pragma unroll
        for (int k = 0; k < 16; ++k) {
            float4 a4 = *(const float4*)&As[k][ty * 4];
            float4 b4 = *(const float4*)&Bs[k][tx * 4];
            float aa[4] = {a4.x, a4.y, a4.z, a4.w};
            float bb[4] = {b4.x, b4.y, b4.z, b4.w};
#pragma unroll
            for (int i = 0; i < 4; ++i)
#pragma unroll
                for (int j = 0; j < 4; ++j)
                    acc[i][j] = fmaf(aa[i], bb[j], acc[i][j]);
        }
    }

    const int row0 = bm0 + ty * 4;
    const int col0 = bn0 + tx * 4;
    float4 bsv = *(const float4*)(bias + col0);
#pragma unroll
    for (int i = 0; i < 4; ++i) {
        float4 o;
        o.x = acc[i][0] + bsv.x;
        o.y = acc[i][1] + bsv.y;
        o.z = acc[i][2] + bsv.z;
        o.w = acc[i][3] + bsv.w;
        if (HAS_RES) {
            float4 rv = *(const float4*)(Rres + (size_t)(row0 + i) * Nn + col0);
            o.x += rv.x; o.y += rv.y; o.z += rv.z; o.w += rv.w;
        }
        if (RELU) {
            o.x = fmaxf(o.x, 0.f); o.y = fmaxf(o.y, 0.f);
            o.z = fmaxf(o.z, 0.f); o.w = fmaxf(o.w, 0.f);
        }
        *(float4*)(C + (size_t)(row0 + i) * Nn + col0) = o;
    }
}

// ---------------------------------------------------------------------------
// Flash-style attention. One block per (b, h, 64-row Q block). 256 threads.
// Thread t: row r = t>>2 (0..63), quarter qt = t&3.
//   scores: thread computes 16 keys (qt*16..) for its row.
//   PV: thread accumulates 8 head-dims (qt*8..) for its row.
// qkv layout: [B, S, 3D]; q at +h*32, k at +D+h*32, v at +2D+h*32.
// ---------------------------------------------------------------------------
__global__ __launch_bounds__(256)
void attn_k(const float* __restrict__ qkv, float* __restrict__ ctx)
{
    __shared__ float Qs[64][36];   // +4 pad: conflict-free, rows 16B-aligned
    __shared__ float Ks[64][36];
    __shared__ float Vs[64][36];
    __shared__ float Ps[64][65];   // +1 pad

    const int blk = blockIdx.x;
    const int qb = blk & 15;
    const int h  = (blk >> 4) & 7;
    const int b  = blk >> 7;
    const int t  = threadIdx.x;
    const int r  = t >> 2;
    const int qt = t & 3;
    const int q0 = qb * 64;

    // load Q block: thread loads row lr, 8 dims at ld
    {
        const int lr = t >> 2, ld = (t & 3) * 8;
        const float* src = qkv + ((size_t)b * Ss + q0 + lr) * D3 + h * HD + ld;
        *(float4*)&Qs[lr][ld]     = *(const float4*)(src);
        *(float4*)&Qs[lr][ld + 4] = *(const float4*)(src + 4);
    }

    float acc[8] = {};
    float m_old = -1e30f, l = 0.f;
    const float scale = 0.17677669529663687f;  // 1/sqrt(32)

    for (int kt = 0; kt < 16; ++kt) {
        const int k0 = kt * 64;
        __syncthreads();   // prior-tile reads done (also fences Q store on kt=0)
        {
            const int lr = t >> 2, ld = (t & 3) * 8;
            const float* kb = qkv + ((size_t)b * Ss + k0 + lr) * D3 + Dd + h * HD + ld;
            const float* vb = qkv + ((size_t)b * Ss + k0 + lr) * D3 + 2 * Dd + h * HD + ld;
            float4 k0v = *(const float4*)kb, k1v = *(const float4*)(kb + 4);
            float4 v0v = *(const float4*)vb, v1v = *(const float4*)(vb + 4);
            *(float4*)&Ks[lr][ld]     = k0v;
            *(float4*)&Ks[lr][ld + 4] = k1v;
            *(float4*)&Vs[lr][ld]     = v0v;
            *(float4*)&Vs[lr][ld + 4] = v1v;
        }
        __syncthreads();

        // hoist Q row into registers
        float4 qr0 = *(const float4*)&Qs[r][0];
        float4 qr1 = *(const float4*)&Qs[r][4];
        float4 qr2 = *(const float4*)&Qs[r][8];
        float4 qr3 = *(const float4*)&Qs[r][12];
        float4 qr4 = *(const float4*)&Qs[r][16];
        float4 qr5 = *(const float4*)&Qs[r][20];
        float4 qr6 = *(const float4*)&Qs[r][24];
        float4 qr7 = *(const float4*)&Qs[r][28];

        float sreg[16];
#pragma unroll
        for (int jj = 0; jj < 16; ++jj) {
            const int j = qt * 16 + jj;
            float dot = 0.f;
            float4 kv;
            kv = *(const float4*)&Ks[j][0];
            dot = fmaf(qr0.x, kv.x, dot); dot = fmaf(qr0.y, kv.y, dot);
            dot = fmaf(qr0.z, kv.z, dot); dot = fmaf(qr0.w, kv.w, dot);
            kv = *(const float4*)&Ks[j][4];
            dot = fmaf(qr1.x, kv.x, dot); dot = fmaf(qr1.y, kv.y, dot);
            dot = fmaf(qr1.z, kv.z, dot); dot = fmaf(qr1.w, kv.w, dot);
            kv = *(const float4*)&Ks[j][8];
            dot = fmaf(qr2.x, kv.x, dot); dot = fmaf(qr2.y, kv.y, dot);
            dot = fmaf(qr2.z, kv.z, dot); dot = fmaf(qr2.w, kv.w, dot);
            kv = *(const float4*)&Ks[j][12];
            dot = fmaf(qr3.x, kv.x, dot); dot = fmaf(qr3.y, kv.y, dot);
            dot = fmaf(qr3.z, kv.z, dot); dot = fmaf(qr3.w, kv.w, dot);
            kv = *(const float4*)&Ks[j][16];
            dot = fmaf(qr4.x, kv.x, dot); dot = fmaf(qr4.y, kv.y, dot);
            dot = fmaf(qr4.z, kv.z, dot); dot = fmaf(qr4.w, kv.w, dot);
            kv = *(const float4*)&Ks[j][20];
            dot = fmaf(qr5.x, kv.x, dot); dot = fmaf(qr5.y, kv.y, dot);
            dot = fmaf(qr5.z, kv.z, dot); dot = fmaf(qr5.w, kv.w, dot);
            kv = *(const float4*)&Ks[j][24];
            dot = fmaf(qr6.x, kv.x, dot); dot = fmaf(qr6.y, kv.y, dot);
            dot = fmaf(qr6.z, kv.z, dot); dot = fmaf(qr6.w, kv.w, dot);
            kv = *(const float4*)&Ks[j][28];
            dot = fmaf(qr7.x, kv.x, dot); dot = fmaf(qr7.y, kv.y, dot);
            dot = fmaf(qr7.z, kv.z, dot); dot = fmaf(qr7.w, kv.w, dot);
            sreg[jj] = dot * scale;
        }

        // row max across the 4 quarter-lanes (lanes 4r..4r+3, same wave)
        float tmax = sreg[0];
#pragma unroll
        for (int jj = 1; jj < 16; ++jj) tmax = fmaxf(tmax, sreg[jj]);
        tmax = fmaxf(tmax, __shfl_xor(tmax, 1));
        tmax = fmaxf(tmax, __shfl_xor(tmax, 2));

        const float m_new = fmaxf(m_old, tmax);
        const float resc  = __expf(m_old - m_new);
        float psum = 0.f;
#pragma unroll
        for (int jj = 0; jj < 16; ++jj) {
            float p = __expf(sreg[jj] - m_new);
            sreg[jj] = p;
            psum += p;
        }
        psum += __shfl_xor(psum, 1);
        psum += __shfl_xor(psum, 2);
        l = l * resc + psum;
        m_old = m_new;
#pragma unroll
        for (int dd = 0; dd < 8; ++dd) acc[dd] *= resc;

#pragma unroll
        for (int jj = 0; jj < 16; ++jj) Ps[r][qt * 16 + jj] = sreg[jj];
        __syncthreads();   // P visible (cheap safety; also keeps waves in phase)

        // PV: acc[0..7] over dims qt*8..qt*8+7
#pragma unroll 8
        for (int j = 0; j < 64; ++j) {
            const float p = Ps[r][j];
            float4 v0 = *(const float4*)&Vs[j][qt * 8];
            float4 v1 = *(const float4*)&Vs[j][qt * 8 + 4];
            acc[0] = fmaf(p, v0.x, acc[0]); acc[1] = fmaf(p, v0.y, acc[1]);
            acc[2] = fmaf(p, v0.z, acc[2]); acc[3] = fmaf(p, v0.w, acc[3]);
            acc[4] = fmaf(p, v1.x, acc[4]); acc[5] = fmaf(p, v1.y, acc[5]);
            acc[6] = fmaf(p, v1.w * 0.f + v1.z, acc[6]); acc[7] = fmaf(p, v1.w, acc[7]);
        }
    }

    const float inv = 1.0f / l;
    float4 o0, o1;
    o0.x = acc[0] * inv; o0.y = acc[1] * inv; o0.z = acc[2] * inv; o0.w = acc[3] * inv;
    o1.x = acc[4] * inv; o1.y = acc[5] * inv; o1.z = acc[6] * inv; o1.w = acc[7] * inv;
    float* dst = ctx + ((size_t)b * Ss + q0 + r) * Dd + h * HD + qt * 8;
    *(float4*)(dst)     = o0;
    *(float4*)(dst + 4) = o1;
}

// ---------------------------------------------------------------------------
// LayerNorm over D=256. One wave per row (4 rows per 256-thread block).
// Y = (X - mu) / sqrt(var + eps) * g + b
// ---------------------------------------------------------------------------
__global__ __launch_bounds__(256)
void ln_k(const float* __restrict__ X, const float* __restrict__ g,
          const float* __restrict__ be, float* __restrict__ Y)
{
    const int wave = threadIdx.x >> 6;
    const int lane = threadIdx.x & 63;
    const int row  = blockIdx.x * 4 + wave;
    const float* xr = X + (size_t)row * Dd;
    float4 v = *(const float4*)(xr + lane * 4);
    float s = v.x + v.y + v.z + v.w;
#pragma unroll
    for (int off = 32; off; off >>= 1) s += __shfl_xor(s, off);
    const float mu = s * (1.0f / Dd);
    const float d0 = v.x - mu, d1 = v.y - mu, d2 = v.z - mu, d3 = v.w - mu;
    float q = d0 * d0 + d1 * d1 + d2 * d2 + d3 * d3;
#pragma unroll
    for (int off = 32; off; off >>= 1) q += __shfl_xor(q, off);
    const float rstd = rsqrtf(q * (1.0f / Dd) + 1e-5f);
    float4 gg = *(const float4*)(g + lane * 4);
    float4 bb = *(const float4*)(be + lane * 4);
    float4 o;
    o.x = d0 * rstd * gg.x + bb.x;
    o.y = d1 * rstd * gg.y + bb.y;
    o.z = d2 * rstd * gg.z + bb.z;
    o.w = d3 * rstd * gg.w + bb.w;
    *(float4*)(Y + (size_t)row * Dd + lane * 4) = o;
}

// ---------------------------------------------------------------------------
// Embedding: per token row, select mol embedding (tokens 4..131) or action_emb.
// ---------------------------------------------------------------------------
__global__ __launch_bounds__(256)
void embed_k(const int* __restrict__ tok, const float* __restrict__ emb,
             const float* __restrict__ mol_emb, float* __restrict__ X)
{
    const int row = blockIdx.x;          // 0..8191
    const int b   = row >> 10;
    const int tkn = tok[row];
    const float* src;
    if (tkn >= 4 && tkn < 4 + MM)
        src = mol_emb + (size_t)(b * MM + tkn - 4) * Dd;
    else
        src = emb + (size_t)tkn * Dd;
    X[(size_t)row * Dd + threadIdx.x] = src[threadIdx.x];
}

// ---------------------------------------------------------------------------
// Final mean over S: out[b,d] = mean_s x[b,s,d]. Two-stage: zero + atomic add.
// ---------------------------------------------------------------------------
__global__ __launch_bounds__(256)
void zero_k(float* __restrict__ out)
{
    out[blockIdx.x * 256 + threadIdx.x] = 0.f;
}

__global__ __launch_bounds__(256)
void mean_partial_k(const float* __restrict__ X, float* __restrict__ out)
{
    const int b = blockIdx.x;
    const int chunk = blockIdx.y;
    const int d = threadIdx.x;
    float s = 0.f;
    const float* base = X + ((size_t)b * Ss + chunk * 64) * Dd + d;
#pragma unroll 4
    for (int i = 0; i < 64; ++i) s += base[(size_t)i * Dd];
    atomicAdd(out + b * Dd + d, s * (1.0f / Ss));
}

// ---------------------------------------------------------------------------
extern "C" void kernel_launch(void* const* d_in, const int* in_sizes, int n_in,
                              void* d_out, int out_size, void* d_ws, size_t ws_size,
                              hipStream_t stream)
{
    const int*   tok        = (const int*)d_in[0];
    const float* action_emb = (const float*)d_in[1];
    const float* mol_pooler = (const float*)d_in[2];
    const float* mol_W      = (const float*)d_in[3];
    const float* mol_b      = (const float*)d_in[4];
    const float* in_proj_w  = (const float*)d_in[5];
    const float* in_proj_b  = (const float*)d_in[6];
    const float* out_w      = (const float*)d_in[7];
    const float* out_b      = (const float*)d_in[8];
    const float* lin1_w     = (const float*)d_in[9];
    const float* lin1_b     = (const float*)d_in[10];
    const float* lin2_w     = (const float*)d_in[11];
    const float* lin2_b     = (const float*)d_in[12];
    const float* ln1_g      = (const float*)d_in[13];
    const float* ln1_be     = (const float*)d_in[14];
    const float* ln2_g      = (const float*)d_in[15];
    const float* ln2_be     = (const float*)d_in[16];

    float* ws      = (float*)d_ws;
    float* mol_emb = ws;                         // 1024*256
    float* x       = mol_emb + 1024 * 256;       // 8192*256
    float* qkv     = x + ROWS * Dd;              // 8192*768
    float* ctx     = qkv + (size_t)ROWS * D3;    // 8192*256
    float* t1      = ctx + ROWS * Dd;            // 8192*256
    float* t2      = t1 + ROWS * Dd;             // 8192*256
    float* out     = (float*)d_out;

    const dim3 blk(256);

    // mol_linear: [1024,768] @ [768,256] + b
    gemm_k<false, false><<<dim3(Dd / 64, 1024 / 64), blk, 0, stream>>>(
        mol_pooler, mol_W, mol_b, nullptr, mol_emb, 1024, Dd, 768);

    // embedding scatter/select
    embed_k<<<dim3(ROWS), blk, 0, stream>>>(tok, action_emb, mol_emb, x);

    for (int l = 0; l < LL; ++l) {
        // qkv = x @ wqkv + b   [8192,256]x[256,768]
        gemm_k<false, false><<<dim3(D3 / 64, ROWS / 64), blk, 0, stream>>>(
            x, in_proj_w + (size_t)l * Dd * D3, in_proj_b + (size_t)l * D3,
            nullptr, qkv, ROWS, D3, Dd);

        // attention -> ctx
        attn_k<<<dim3(Bb * Hh * (Ss / 64)), blk, 0, stream>>>(qkv, ctx);

        // t1 = x + ctx @ wo + bo
        gemm_k<false, true><<<dim3(Dd / 64, ROWS / 64), blk, 0, stream>>>(
            ctx, out_w + (size_t)l * Dd * Dd, out_b + (size_t)l * Dd,
            x, t1, ROWS, Dd, Dd);

        // x1 = LN(t1) -> reuse ctx
        ln_k<<<dim3(ROWS / 4), blk, 0, stream>>>(t1, ln1_g + l * Dd, ln1_be + l * Dd, ctx);

        // t2 = relu(x1 @ w1 + b1)
        gemm_k<true, false><<<dim3(Dd / 64, ROWS / 64), blk, 0, stream>>>(
            ctx, lin1_w + (size_t)l * Dd * Dd, lin1_b + (size_t)l * Dd,
            nullptr, t2, ROWS, Dd, Dd);

        // t1 = x1 + t2 @ w2 + b2
        gemm_k<false, true><<<dim3(Dd / 64, ROWS / 64), blk, 0, stream>>>(
            t2, lin2_w + (size_t)l * Dd * Dd, lin2_b + (size_t)l * Dd,
            ctx, t1, ROWS, Dd, Dd);

        // x = LN(t1)
        ln_k<<<dim3(ROWS / 4), blk, 0, stream>>>(t1, ln2_g + l * Dd, ln2_be + l * Dd, x);
    }

    // out[1,8,256] = mean over S
    zero_k<<<dim3(out_size / 256), blk, 0, stream>>>(out);
    mean_partial_k<<<dim3(Bb, Ss / 64), blk, 0, stream>>>(x, out);
}

// Round 2
// 1289.568 us; speedup vs baseline: 1.4647x; 1.4647x over previous
//
#include <hip/hip_runtime.h>
#include <math.h>

// Problem constants (from setup_inputs): B=8, S=1024, D=256, H=8, hd=32, L=4, M=128
#define Bb 8
#define Ss 1024
#define Dd 256
#define Hh 8
#define HD 32
#define LL 4
#define MM 128
#define ROWS (Bb*Ss)      // 8192
#define D3 (3*Dd)         // 768

// ---------------------------------------------------------------------------
// Tiled fp32 GEMM: C[M,N] = A[M,K] @ W[K,N] + bias (+ residual) (+ relu)
// Tile 64x64, BK=16, 256 threads, 4x4 micro-tile per thread.
// As leading dim 68: transposed scalar stores 2-way (free), fragment reads
// conflict-free ((17k+ty)%8 spans distinct groups). Bs stride 64: reads 2-way.
// ---------------------------------------------------------------------------
template<bool RELU, bool HAS_RES>
__global__ __launch_bounds__(256)
void gemm_k(const float* __restrict__ A, const float* __restrict__ W,
            const float* __restrict__ bias, const float* __restrict__ Rres,
            float* __restrict__ C, int Mm, int Nn, int Kk)
{
    __shared__ float As[16][68];   // [k][m]  (transposed store, padded)
    __shared__ float Bs[16][64];   // [k][n]

    const int t  = threadIdx.x;
    const int tx = t & 15;         // 0..15  -> col group
    const int ty = t >> 4;         // 0..15  -> row group
    const int bn0 = blockIdx.x * 64;
    const int bm0 = blockIdx.y * 64;

    const int am = t >> 2;         // 0..63 row of A tile
    const int ak = (t & 3) * 4;    // 0,4,8,12
    const int bk = t >> 4;         // 0..15 row of W tile
    const int bn = (t & 15) * 4;   // 0..60

    float acc[4][4] = {};

    for (int k0 = 0; k0 < Kk; k0 += 16) {
        float4 av = *(const float4*)(A + (size_t)(bm0 + am) * Kk + k0 + ak);
        float4 bv = *(const float4*)(W + (size_t)(k0 + bk) * Nn + bn0 + bn);
        __syncthreads();   // previous iteration's reads complete
        As[ak + 0][am] = av.x;
        As[ak + 1][am] = av.y;
        As[ak + 2][am] = av.z;
        As[ak + 3][am] = av.w;
        *(float4*)&Bs[bk][bn] = bv;
        __syncthreads();
#pragma unroll
        for (int k = 0; k < 16; ++k) {
            float4 a4 = *(const float4*)&As[k][ty * 4];
            float4 b4 = *(const float4*)&Bs[k][tx * 4];
            float aa[4] = {a4.x, a4.y, a4.z, a4.w};
            float bb[4] = {b4.x, b4.y, b4.z, b4.w};
#pragma unroll
            for (int i = 0; i < 4; ++i)
#pragma unroll
                for (int j = 0; j < 4; ++j)
                    acc[i][j] = fmaf(aa[i], bb[j], acc[i][j]);
        }
    }

    const int row0 = bm0 + ty * 4;
    const int col0 = bn0 + tx * 4;
    float4 bsv = *(const float4*)(bias + col0);
#pragma unroll
    for (int i = 0; i < 4; ++i) {
        float4 o;
        o.x = acc[i][0] + bsv.x;
        o.y = acc[i][1] + bsv.y;
        o.z = acc[i][2] + bsv.z;
        o.w = acc[i][3] + bsv.w;
        if (HAS_RES) {
            float4 rv = *(const float4*)(Rres + (size_t)(row0 + i) * Nn + col0);
            o.x += rv.x; o.y += rv.y; o.z += rv.z; o.w += rv.w;
        }
        if (RELU) {
            o.x = fmaxf(o.x, 0.f); o.y = fmaxf(o.y, 0.f);
            o.z = fmaxf(o.z, 0.f); o.w = fmaxf(o.w, 0.f);
        }
        *(float4*)(C + (size_t)(row0 + i) * Nn + col0) = o;
    }
}

// ---------------------------------------------------------------------------
// Flash-style attention, conflict-free LDS pattern.
// One block per (b, h, 64-row Q block). 256 threads.
// Thread t = (r, qt): r = t>>2 (q-row 0..63), qt = t&3 (key phase).
// Lane handles keys j = 4*jj + qt (4 CONSECUTIVE rows per wave instruction ->
// bank-group (9j+slot)%8 spans 4 distinct groups -> conflict-free b128 reads).
// Lane accumulates acc[32] (all head dims) for its 16 keys; quad shfl-reduce
// at end merges the 4 phases. No P in LDS, no per-tile P barrier.
// ---------------------------------------------------------------------------
__global__ __launch_bounds__(256)
void attn_k(const float* __restrict__ qkv, float* __restrict__ ctx)
{
    __shared__ float Qs[64][36];
    __shared__ float Ks[64][36];
    __shared__ float Vs[64][36];

    const int blk = blockIdx.x;
    const int qb = blk & 15;
    const int h  = (blk >> 4) & 7;
    const int b  = blk >> 7;
    const int t  = threadIdx.x;
    const int r  = t >> 2;
    const int qt = t & 3;
    const int q0 = qb * 64;
    const int lr = t >> 2, ld = (t & 3) * 8;

    // stage Q block (coalesced), then hoist own row to registers ONCE
    {
        const float* src = qkv + ((size_t)b * Ss + q0 + lr) * D3 + h * HD + ld;
        *(float4*)&Qs[lr][ld]     = *(const float4*)(src);
        *(float4*)&Qs[lr][ld + 4] = *(const float4*)(src + 4);
    }
    __syncthreads();
    float qreg[32];
#pragma unroll
    for (int i = 0; i < 8; ++i)
        *(float4*)&qreg[i * 4] = *(const float4*)&Qs[r][i * 4];

    float acc[32] = {};
    float m_old = -1e30f, l = 0.f;
    const float scale = 0.17677669529663687f;  // 1/sqrt(32)

    for (int kt = 0; kt < 16; ++kt) {
        const int k0 = kt * 64;
        // issue global loads for this tile BEFORE the barrier (latency hides
        // under other waves' prior-tile compute)
        const float* kb = qkv + ((size_t)b * Ss + k0 + lr) * D3 + Dd + h * HD + ld;
        const float* vb = kb + Dd;
        float4 k0v = *(const float4*)kb, k1v = *(const float4*)(kb + 4);
        float4 v0v = *(const float4*)vb, v1v = *(const float4*)(vb + 4);
        __syncthreads();   // prior-tile LDS reads complete
        *(float4*)&Ks[lr][ld]     = k0v;
        *(float4*)&Ks[lr][ld + 4] = k1v;
        *(float4*)&Vs[lr][ld]     = v0v;
        *(float4*)&Vs[lr][ld + 4] = v1v;
        __syncthreads();

        // scores: 16 keys (j = 4*jj + qt), conflict-free Ks reads
        float sreg[16];
#pragma unroll
        for (int jj = 0; jj < 16; ++jj) {
            const int j = jj * 4 + qt;
            float dot = 0.f;
#pragma unroll
            for (int i2 = 0; i2 < 8; ++i2) {
                float4 kv = *(const float4*)&Ks[j][i2 * 4];
                dot = fmaf(qreg[i2 * 4 + 0], kv.x, dot);
                dot = fmaf(qreg[i2 * 4 + 1], kv.y, dot);
                dot = fmaf(qreg[i2 * 4 + 2], kv.z, dot);
                dot = fmaf(qreg[i2 * 4 + 3], kv.w, dot);
            }
            sreg[jj] = dot * scale;
        }

        // online softmax: row stats across the quad (lanes 4r..4r+3)
        float tmax = sreg[0];
#pragma unroll
        for (int jj = 1; jj < 16; ++jj) tmax = fmaxf(tmax, sreg[jj]);
        tmax = fmaxf(tmax, __shfl_xor(tmax, 1));
        tmax = fmaxf(tmax, __shfl_xor(tmax, 2));

        const float m_new = fmaxf(m_old, tmax);
        const float resc  = __expf(m_old - m_new);
        float psum = 0.f;
#pragma unroll
        for (int jj = 0; jj < 16; ++jj) {
            float p = __expf(sreg[jj] - m_new);
            sreg[jj] = p;
            psum += p;
        }
        psum += __shfl_xor(psum, 1);
        psum += __shfl_xor(psum, 2);
        l = l * resc + psum;
        m_old = m_new;
#pragma unroll
        for (int dd = 0; dd < 32; ++dd) acc[dd] *= resc;

        // PV: lane's own p against all 32 dims (conflict-free Vs reads)
#pragma unroll
        for (int jj = 0; jj < 16; ++jj) {
            const int j = jj * 4 + qt;
            const float p = sreg[jj];
#pragma unroll
            for (int i2 = 0; i2 < 8; ++i2) {
                float4 vv = *(const float4*)&Vs[j][i2 * 4];
                acc[i2 * 4 + 0] = fmaf(p, vv.x, acc[i2 * 4 + 0]);
                acc[i2 * 4 + 1] = fmaf(p, vv.y, acc[i2 * 4 + 1]);
                acc[i2 * 4 + 2] = fmaf(p, vv.z, acc[i2 * 4 + 2]);
                acc[i2 * 4 + 3] = fmaf(p, vv.w, acc[i2 * 4 + 3]);
            }
        }
    }

    // merge the 4 key phases (quad butterfly), once per block
#pragma unroll
    for (int dd = 0; dd < 32; ++dd) {
        acc[dd] += __shfl_xor(acc[dd], 1);
        acc[dd] += __shfl_xor(acc[dd], 2);
    }

    const float inv = 1.0f / l;
    float o[8];
    if (qt == 0) {
#pragma unroll
        for (int i = 0; i < 8; ++i) o[i] = acc[i];
    } else if (qt == 1) {
#pragma unroll
        for (int i = 0; i < 8; ++i) o[i] = acc[8 + i];
    } else if (qt == 2) {
#pragma unroll
        for (int i = 0; i < 8; ++i) o[i] = acc[16 + i];
    } else {
#pragma unroll
        for (int i = 0; i < 8; ++i) o[i] = acc[24 + i];
    }
    float4 o0, o1;
    o0.x = o[0] * inv; o0.y = o[1] * inv; o0.z = o[2] * inv; o0.w = o[3] * inv;
    o1.x = o[4] * inv; o1.y = o[5] * inv; o1.z = o[6] * inv; o1.w = o[7] * inv;
    float* dst = ctx + ((size_t)b * Ss + q0 + r) * Dd + h * HD + qt * 8;
    *(float4*)(dst)     = o0;
    *(float4*)(dst + 4) = o1;
}

// ---------------------------------------------------------------------------
// LayerNorm over D=256. One wave per row (4 rows per 256-thread block).
// ---------------------------------------------------------------------------
__global__ __launch_bounds__(256)
void ln_k(const float* __restrict__ X, const float* __restrict__ g,
          const float* __restrict__ be, float* __restrict__ Y)
{
    const int wave = threadIdx.x >> 6;
    const int lane = threadIdx.x & 63;
    const int row  = blockIdx.x * 4 + wave;
    const float* xr = X + (size_t)row * Dd;
    float4 v = *(const float4*)(xr + lane * 4);
    float s = v.x + v.y + v.z + v.w;
#pragma unroll
    for (int off = 32; off; off >>= 1) s += __shfl_xor(s, off);
    const float mu = s * (1.0f / Dd);
    const float d0 = v.x - mu, d1 = v.y - mu, d2 = v.z - mu, d3 = v.w - mu;
    float q = d0 * d0 + d1 * d1 + d2 * d2 + d3 * d3;
#pragma unroll
    for (int off = 32; off; off >>= 1) q += __shfl_xor(q, off);
    const float rstd = rsqrtf(q * (1.0f / Dd) + 1e-5f);
    float4 gg = *(const float4*)(g + lane * 4);
    float4 bb = *(const float4*)(be + lane * 4);
    float4 o;
    o.x = d0 * rstd * gg.x + bb.x;
    o.y = d1 * rstd * gg.y + bb.y;
    o.z = d2 * rstd * gg.z + bb.z;
    o.w = d3 * rstd * gg.w + bb.w;
    *(float4*)(Y + (size_t)row * Dd + lane * 4) = o;
}

// ---------------------------------------------------------------------------
// Embedding: per token row, select mol embedding (tokens 4..131) or action_emb.
// ---------------------------------------------------------------------------
__global__ __launch_bounds__(256)
void embed_k(const int* __restrict__ tok, const float* __restrict__ emb,
             const float* __restrict__ mol_emb, float* __restrict__ X)
{
    const int row = blockIdx.x;          // 0..8191
    const int b   = row >> 10;
    const int tkn = tok[row];
    const float* src;
    if (tkn >= 4 && tkn < 4 + MM)
        src = mol_emb + (size_t)(b * MM + tkn - 4) * Dd;
    else
        src = emb + (size_t)tkn * Dd;
    X[(size_t)row * Dd + threadIdx.x] = src[threadIdx.x];
}

// ---------------------------------------------------------------------------
// Final mean over S: out[b,d] = mean_s x[b,s,d]. Two-stage: zero + atomic add.
// ---------------------------------------------------------------------------
__global__ __launch_bounds__(256)
void zero_k(float* __restrict__ out)
{
    out[blockIdx.x * 256 + threadIdx.x] = 0.f;
}

__global__ __launch_bounds__(256)
void mean_partial_k(const float* __restrict__ X, float* __restrict__ out)
{
    const int b = blockIdx.x;
    const int chunk = blockIdx.y;
    const int d = threadIdx.x;
    float s = 0.f;
    const float* base = X + ((size_t)b * Ss + chunk * 64) * Dd + d;
#pragma unroll 4
    for (int i = 0; i < 64; ++i) s += base[(size_t)i * Dd];
    atomicAdd(out + b * Dd + d, s * (1.0f / Ss));
}

// ---------------------------------------------------------------------------
extern "C" void kernel_launch(void* const* d_in, const int* in_sizes, int n_in,
                              void* d_out, int out_size, void* d_ws, size_t ws_size,
                              hipStream_t stream)
{
    const int*   tok        = (const int*)d_in[0];
    const float* action_emb = (const float*)d_in[1];
    const float* mol_pooler = (const float*)d_in[2];
    const float* mol_W      = (const float*)d_in[3];
    const float* mol_b      = (const float*)d_in[4];
    const float* in_proj_w  = (const float*)d_in[5];
    const float* in_proj_b  = (const float*)d_in[6];
    const float* out_w      = (const float*)d_in[7];
    const float* out_b      = (const float*)d_in[8];
    const float* lin1_w     = (const float*)d_in[9];
    const float* lin1_b     = (const float*)d_in[10];
    const float* lin2_w     = (const float*)d_in[11];
    const float* lin2_b     = (const float*)d_in[12];
    const float* ln1_g      = (const float*)d_in[13];
    const float* ln1_be     = (const float*)d_in[14];
    const float* ln2_g      = (const float*)d_in[15];
    const float* ln2_be     = (const float*)d_in[16];

    float* ws      = (float*)d_ws;
    float* mol_emb = ws;                         // 1024*256
    float* x       = mol_emb + 1024 * 256;       // 8192*256
    float* qkv     = x + ROWS * Dd;              // 8192*768
    float* ctx     = qkv + (size_t)ROWS * D3;    // 8192*256
    float* t1      = ctx + ROWS * Dd;            // 8192*256
    float* t2      = t1 + ROWS * Dd;             // 8192*256
    float* out     = (float*)d_out;

    const dim3 blk(256);

    // mol_linear: [1024,768] @ [768,256] + b
    gemm_k<false, false><<<dim3(Dd / 64, 1024 / 64), blk, 0, stream>>>(
        mol_pooler, mol_W, mol_b, nullptr, mol_emb, 1024, Dd, 768);

    // embedding scatter/select
    embed_k<<<dim3(ROWS), blk, 0, stream>>>(tok, action_emb, mol_emb, x);

    for (int l = 0; l < LL; ++l) {
        // qkv = x @ wqkv + b   [8192,256]x[256,768]
        gemm_k<false, false><<<dim3(D3 / 64, ROWS / 64), blk, 0, stream>>>(
            x, in_proj_w + (size_t)l * Dd * D3, in_proj_b + (size_t)l * D3,
            nullptr, qkv, ROWS, D3, Dd);

        // attention -> ctx
        attn_k<<<dim3(Bb * Hh * (Ss / 64)), blk, 0, stream>>>(qkv, ctx);

        // t1 = x + ctx @ wo + bo
        gemm_k<false, true><<<dim3(Dd / 64, ROWS / 64), blk, 0, stream>>>(
            ctx, out_w + (size_t)l * Dd * Dd, out_b + (size_t)l * Dd,
            x, t1, ROWS, Dd, Dd);

        // x1 = LN(t1) -> reuse ctx
        ln_k<<<dim3(ROWS / 4), blk, 0, stream>>>(t1, ln1_g + l * Dd, ln1_be + l * Dd, ctx);

        // t2 = relu(x1 @ w1 + b1)
        gemm_k<true, false><<<dim3(Dd / 64, ROWS / 64), blk, 0, stream>>>(
            ctx, lin1_w + (size_t)l * Dd * Dd, lin1_b + (size_t)l * Dd,
            nullptr, t2, ROWS, Dd, Dd);

        // t1 = x1 + t2 @ w2 + b2
        gemm_k<false, true><<<dim3(Dd / 64, ROWS / 64), blk, 0, stream>>>(
            t2, lin2_w + (size_t)l * Dd * Dd, lin2_b + (size_t)l * Dd,
            ctx, t1, ROWS, Dd, Dd);

        // x = LN(t1)
        ln_k<<<dim3(ROWS / 4), blk, 0, stream>>>(t1, ln2_g + l * Dd, ln2_be + l * Dd, x);
    }

    // out[1,8,256] = mean over S
    zero_k<<<dim3(out_size / 256), blk, 0, stream>>>(out);
    mean_partial_k<<<dim3(Bb, Ss / 64), blk, 0, stream>>>(x, out);
}

// Round 14
// 458.269 us; speedup vs baseline: 4.1216x; 2.8140x over previous
//
#include <hip/hip_runtime.h>
#include <math.h>

// Problem constants: B=8, S=1024, D=256, H=8, hd=32, L=4, M=128
#define Bb 8
#define Ss 1024
#define Dd 256
#define Hh 8
#define LL 4
#define MM 128
#define ROWS (Bb*Ss)      // 8192
#define D3 (3*Dd)         // 768

typedef __attribute__((ext_vector_type(8))) short  short8;   // 8 bf16 = one MFMA operand frag
typedef __attribute__((ext_vector_type(4))) float  f32x4;    // MFMA accumulator
typedef __attribute__((ext_vector_type(4))) ushort us4v;

__device__ __forceinline__ ushort f2bf(float f) {
    uint u = __float_as_uint(f);
    u += 0x7FFFu + ((u >> 16) & 1u);     // RNE
    return (ushort)(u >> 16);
}

// ---------------------------------------------------------------------------
// bf16 MFMA GEMM: C[M,N] = A[M,K] @ W^T[N,K]^T + bias (+res)(+relu)
// Block tile 128(M)x64(N), 4 waves (2x2), wave tile 64x32, BK=64.
// LDS rows padded to 72 bf16 (36 dwords == 4 mod 32 -> 2-way, free).
// ---------------------------------------------------------------------------
template<bool RELU, bool HAS_RES, bool OUTF, bool OUTB>
__global__ __launch_bounds__(256)
void bgemm_k(const ushort* __restrict__ A, const ushort* __restrict__ Wt,
             const float* __restrict__ bias, const float* Rres,
             float* Cf, ushort* Cb, int Nn, int Kk)
{
    __shared__ ushort As[128 * 72];
    __shared__ ushort Bs[64 * 72];

    const int t  = threadIdx.x;
    const int l  = t & 63;
    const int w  = t >> 6;
    const int wr = w >> 1, wc = w & 1;
    const int g  = l >> 4, qi = l & 15;
    const int bn0 = blockIdx.x * 64;
    const int bm0 = blockIdx.y * 128;

    const int arow = t >> 1, akc = (t & 1) * 32;   // A: 32 elems/thread
    const int brow = t >> 2, bch = (t & 3) * 16;   // B: 16 elems/thread

    f32x4 acc[4][2];
#pragma unroll
    for (int mi = 0; mi < 4; ++mi)
#pragma unroll
        for (int ni = 0; ni < 2; ++ni)
            acc[mi][ni] = (f32x4)(0.f);

    for (int k0 = 0; k0 < Kk; k0 += 64) {
        const ushort* ga = A + (size_t)(bm0 + arow) * Kk + k0 + akc;
        short8 av0 = *(const short8*)(ga);
        short8 av1 = *(const short8*)(ga + 8);
        short8 av2 = *(const short8*)(ga + 16);
        short8 av3 = *(const short8*)(ga + 24);
        const ushort* gb = Wt + (size_t)(bn0 + brow) * Kk + k0 + bch;
        short8 bv0 = *(const short8*)(gb);
        short8 bv1 = *(const short8*)(gb + 8);
        __syncthreads();                 // prior iteration's frag reads done
        *(short8*)(As + arow * 72 + akc)      = av0;
        *(short8*)(As + arow * 72 + akc + 8)  = av1;
        *(short8*)(As + arow * 72 + akc + 16) = av2;
        *(short8*)(As + arow * 72 + akc + 24) = av3;
        *(short8*)(Bs + brow * 72 + bch)      = bv0;
        *(short8*)(Bs + brow * 72 + bch + 8)  = bv1;
        __syncthreads();
#pragma unroll
        for (int ks = 0; ks < 2; ++ks) {
            short8 af[4], bfr[2];
#pragma unroll
            for (int mi = 0; mi < 4; ++mi)
                af[mi] = *(const short8*)(As + (wr*64 + mi*16 + qi)*72 + ks*32 + g*8);
#pragma unroll
            for (int ni = 0; ni < 2; ++ni)
                bfr[ni] = *(const short8*)(Bs + (wc*32 + ni*16 + qi)*72 + ks*32 + g*8);
#pragma unroll
            for (int mi = 0; mi < 4; ++mi)
#pragma unroll
                for (int ni = 0; ni < 2; ++ni)
                    acc[mi][ni] = __builtin_amdgcn_mfma_f32_16x16x32_bf16(
                        af[mi], bfr[ni], acc[mi][ni], 0, 0, 0);
        }
    }

    // epilogue: D row = (lane>>4)*4 + reg, col = lane&15
#pragma unroll
    for (int ni = 0; ni < 2; ++ni) {
        const int col = bn0 + wc*32 + ni*16 + qi;
        const float bsv = bias[col];
#pragma unroll
        for (int mi = 0; mi < 4; ++mi) {
#pragma unroll
            for (int r = 0; r < 4; ++r) {
                const int row = bm0 + wr*64 + mi*16 + g*4 + r;
                float v = acc[mi][ni][r] + bsv;
                if (HAS_RES) v += Rres[(size_t)row * Nn + col];
                if (RELU)    v = fmaxf(v, 0.f);
                if (OUTF) Cf[(size_t)row * Nn + col] = v;
                if (OUTB) Cb[(size_t)row * Nn + col] = f2bf(v);
            }
        }
    }
}

// ---------------------------------------------------------------------------
// MFMA flash attention. Block = (b, h, 64 q-rows); wave = 16 q-rows.
// S^T = mfma(K, Q): lane (g,qi) holds scores for q=qi at kv = 16f + 4g + r.
// V staged transposed with column bit-permutation tau(c)=[c5,c2,c4,c3,c1,c0]
// so P fragments for PV assemble lane-locally (no cross-lane exchange).
// Online softmax, fp32 stats, defer-max (8 nats).
// ---------------------------------------------------------------------------
__global__ __launch_bounds__(256)
void attn_mfma_k(const ushort* __restrict__ qkv, ushort* __restrict__ ctx)
{
    __shared__ ushort Ks[64 * 40];   // rows padded to 40 bf16 (20 dw) -> 2-way
    __shared__ ushort Vt[32 * 72];   // [d][kv'] rows padded to 72 bf16

    const int idx = blockIdx.x;
    const int qc = idx & 15;
    const int h  = (idx >> 4) & 7;
    const int b  = idx >> 7;
    const int t  = threadIdx.x;
    const int l  = t & 63;
    const int w  = t >> 6;
    const int g  = l >> 4, qi = l & 15;
    const int q0w = qc * 64 + w * 16;
    const size_t bS = (size_t)b * Ss;

    // Q fragment (B operand): lane holds Q[q0w+qi][g*8 .. g*8+7]
    short8 qfrag = *(const short8*)(qkv + (bS + q0w + qi) * D3 + h * 32 + g * 8);

    f32x4 oct[2];
    oct[0] = (f32x4)(0.f);
    oct[1] = (f32x4)(0.f);
    float m2 = -3.0e38f, lsum = 0.f;
    const float sc = 0.17677669529663687f;   // 1/sqrt(32)

    const int kRow = t >> 2, kCh = (t & 3) * 8;      // K staging
    const int vC   = (t >> 3) * 2, vDc = (t & 7) * 4; // Vt staging (col pair, 4 d's)
    const int kap0 = 32*(vC>>5) + 16*((vC>>2)&1) + 4*((vC>>3)&3) + (vC&3);  // tau(vC)

    for (int kt = 0; kt < 16; ++kt) {
        const int k0 = kt * 64;
        // issue global loads before the barrier
        short8 kv8 = *(const short8*)(qkv + (bS + k0 + kRow) * D3 + Dd + h * 32 + kCh);
        const ushort* vp0 = qkv + (bS + k0 + kap0) * D3 + 2 * Dd + h * 32 + vDc;
        us4v v0 = *(const us4v*)(vp0);
        us4v v1 = *(const us4v*)(vp0 + D3);
        __syncthreads();                 // prior tile's LDS reads done
        *(short8*)(Ks + kRow * 40 + kCh) = kv8;
#pragma unroll
        for (int i = 0; i < 4; ++i) {
            uint dwv = (uint)v0[i] | ((uint)v1[i] << 16);
            *(uint*)(Vt + (vDc + i) * 72 + vC) = dwv;
        }
        __syncthreads();

        // S^T tile: 4 MFMAs
        f32x4 zero = (f32x4)(0.f);
        f32x4 sacc[4];
#pragma unroll
        for (int f = 0; f < 4; ++f) {
            short8 kf = *(const short8*)(Ks + (f * 16 + qi) * 40 + g * 8);
            sacc[f] = __builtin_amdgcn_mfma_f32_16x16x32_bf16(kf, qfrag, zero, 0, 0, 0);
        }

        // row max for q = qi (16 local + quad groups via xor16/32)
        float mx = sacc[0][0];
#pragma unroll
        for (int f = 0; f < 4; ++f)
#pragma unroll
            for (int r = 0; r < 4; ++r) mx = fmaxf(mx, sacc[f][r]);
        mx = fmaxf(mx, __shfl_xor(mx, 16));
        mx = fmaxf(mx, __shfl_xor(mx, 32));
        const float mxs = mx * sc;

        if (!__all(mxs <= m2 + 8.0f)) {   // defer-max: rescale only on real growth
            const float mnew = fmaxf(m2, mxs);
            const float resc = __expf(m2 - mnew);
            m2 = mnew;
            lsum *= resc;
            const float rr0 = __shfl(resc, g * 4 + 0);
            const float rr1 = __shfl(resc, g * 4 + 1);
            const float rr2 = __shfl(resc, g * 4 + 2);
            const float rr3 = __shfl(resc, g * 4 + 3);
#pragma unroll
            for (int df = 0; df < 2; ++df) {
                oct[df][0] *= rr0; oct[df][1] *= rr1;
                oct[df][2] *= rr2; oct[df][3] *= rr3;
            }
        }

        float e[4][4]; float psum = 0.f;
#pragma unroll
        for (int f = 0; f < 4; ++f)
#pragma unroll
            for (int r = 0; r < 4; ++r) {
                float p = __expf(sacc[f][r] * sc - m2);
                e[f][r] = p; psum += p;
            }
        psum += __shfl_xor(psum, 16);
        psum += __shfl_xor(psum, 32);
        lsum += psum;

        // pack P into lane-local A-operand frags (slot j: f=2t2+(j>>2), r=j&3)
        union { short8 s; uint u[4]; } pa[2];
#pragma unroll
        for (int t2 = 0; t2 < 2; ++t2) {
            pa[t2].u[0] = (uint)f2bf(e[2*t2][0])   | ((uint)f2bf(e[2*t2][1])   << 16);
            pa[t2].u[1] = (uint)f2bf(e[2*t2][2])   | ((uint)f2bf(e[2*t2][3])   << 16);
            pa[t2].u[2] = (uint)f2bf(e[2*t2+1][0]) | ((uint)f2bf(e[2*t2+1][1]) << 16);
            pa[t2].u[3] = (uint)f2bf(e[2*t2+1][2]) | ((uint)f2bf(e[2*t2+1][3]) << 16);
        }

        // PV: 4 MFMAs
#pragma unroll
        for (int t2 = 0; t2 < 2; ++t2)
#pragma unroll
            for (int df = 0; df < 2; ++df) {
                short8 vf = *(const short8*)(Vt + (df * 16 + qi) * 72 + t2 * 32 + g * 8);
                oct[df] = __builtin_amdgcn_mfma_f32_16x16x32_bf16(pa[t2].s, vf, oct[df], 0, 0, 0);
            }
    }

    const float inv = 1.0f / lsum;
    const float iv0 = __shfl(inv, g * 4 + 0);
    const float iv1 = __shfl(inv, g * 4 + 1);
    const float iv2 = __shfl(inv, g * 4 + 2);
    const float iv3 = __shfl(inv, g * 4 + 3);
#pragma unroll
    for (int df = 0; df < 2; ++df) {
        const int dcol = h * 32 + df * 16 + qi;
        ctx[(bS + q0w + g*4 + 0) * Dd + dcol] = f2bf(oct[df][0] * iv0);
        ctx[(bS + q0w + g*4 + 1) * Dd + dcol] = f2bf(oct[df][1] * iv1);
        ctx[(bS + q0w + g*4 + 2) * Dd + dcol] = f2bf(oct[df][2] * iv2);
        ctx[(bS + q0w + g*4 + 3) * Dd + dcol] = f2bf(oct[df][3] * iv3);
    }
}

// ---------------------------------------------------------------------------
// LayerNorm (fp32 in -> fp32 + bf16 out). One wave per row.
// ---------------------------------------------------------------------------
__global__ __launch_bounds__(256)
void ln_k(const float* __restrict__ X, const float* __restrict__ g,
          const float* __restrict__ be, float* __restrict__ Y,
          ushort* __restrict__ Ybf)
{
    const int wave = threadIdx.x >> 6;
    const int lane = threadIdx.x & 63;
    const int row  = blockIdx.x * 4 + wave;
    const float* xr = X + (size_t)row * Dd;
    float4 v = *(const float4*)(xr + lane * 4);
    float s = v.x + v.y + v.z + v.w;
#pragma unroll
    for (int off = 32; off; off >>= 1) s += __shfl_xor(s, off);
    const float mu = s * (1.0f / Dd);
    const float d0 = v.x - mu, d1 = v.y - mu, d2 = v.z - mu, d3 = v.w - mu;
    float q = d0*d0 + d1*d1 + d2*d2 + d3*d3;
#pragma unroll
    for (int off = 32; off; off >>= 1) q += __shfl_xor(q, off);
    const float rstd = rsqrtf(q * (1.0f / Dd) + 1e-5f);
    float4 gg = *(const float4*)(g + lane * 4);
    float4 bb = *(const float4*)(be + lane * 4);
    float4 o;
    o.x = d0 * rstd * gg.x + bb.x;
    o.y = d1 * rstd * gg.y + bb.y;
    o.z = d2 * rstd * gg.z + bb.z;
    o.w = d3 * rstd * gg.w + bb.w;
    *(float4*)(Y + (size_t)row * Dd + lane * 4) = o;
    us4v ob = {f2bf(o.x), f2bf(o.y), f2bf(o.z), f2bf(o.w)};
    *(us4v*)(Ybf + (size_t)row * Dd + lane * 4) = ob;
}

// ---------------------------------------------------------------------------
// Embedding select (fp32 + bf16 shadow out)
// ---------------------------------------------------------------------------
__global__ __launch_bounds__(256)
void embed_k(const int* __restrict__ tok, const float* __restrict__ emb,
             const float* __restrict__ mol_emb, float* __restrict__ X,
             ushort* __restrict__ Xb)
{
    const int row = blockIdx.x;
    const int b   = row >> 10;
    const int tkn = tok[row];
    const float* src;
    if (tkn >= 4 && tkn < 4 + MM)
        src = mol_emb + (size_t)(b * MM + tkn - 4) * Dd;
    else
        src = emb + (size_t)tkn * Dd;
    const float v = src[threadIdx.x];
    X[(size_t)row * Dd + threadIdx.x]  = v;
    Xb[(size_t)row * Dd + threadIdx.x] = f2bf(v);
}

// ---------------------------------------------------------------------------
// Weight transpose + bf16 convert: W[K][N] f32 -> Wt[N][K] bf16 (batched)
// ---------------------------------------------------------------------------
__global__ __launch_bounds__(256)
void transpose_w_k(const float* __restrict__ W, ushort* __restrict__ Wt,
                   int Kk, int Nn, int inStride, int outStride)
{
    __shared__ float T[32][33];
    const float* Wz = W + (size_t)blockIdx.z * inStride;
    ushort* Wtz = Wt + (size_t)blockIdx.z * outStride;
    const int k0 = blockIdx.x * 32, n0 = blockIdx.y * 32;
    const int r = threadIdx.x >> 3, c4 = (threadIdx.x & 7) * 4;
    float4 v = *(const float4*)(Wz + (size_t)(k0 + r) * Nn + n0 + c4);
    T[r][c4+0] = v.x; T[r][c4+1] = v.y; T[r][c4+2] = v.z; T[r][c4+3] = v.w;
    __syncthreads();
    us4v o = {f2bf(T[c4+0][r]), f2bf(T[c4+1][r]), f2bf(T[c4+2][r]), f2bf(T[c4+3][r])};
    *(us4v*)(Wtz + (size_t)(n0 + r) * Kk + k0 + c4) = o;
}

// f32 -> bf16 elementwise (mol_pooler)
__global__ __launch_bounds__(256)
void cvt_bf_k(const float* __restrict__ in, ushort* __restrict__ out)
{
    const int gid = blockIdx.x * 256 + threadIdx.x;
    float4 v = ((const float4*)in)[gid];
    us4v o = {f2bf(v.x), f2bf(v.y), f2bf(v.z), f2bf(v.w)};
    ((us4v*)out)[gid] = o;
}

// ---------------------------------------------------------------------------
// Final mean over S
// ---------------------------------------------------------------------------
__global__ __launch_bounds__(256)
void zero_k(float* __restrict__ out)
{
    out[blockIdx.x * 256 + threadIdx.x] = 0.f;
}

__global__ __launch_bounds__(256)
void mean_partial_k(const float* __restrict__ X, float* __restrict__ out)
{
    const int b = blockIdx.x;
    const int chunk = blockIdx.y;
    const int d = threadIdx.x;
    float s = 0.f;
    const float* base = X + ((size_t)b * Ss + chunk * 64) * Dd + d;
#pragma unroll 4
    for (int i = 0; i < 64; ++i) s += base[(size_t)i * Dd];
    atomicAdd(out + b * Dd + d, s * (1.0f / Ss));
}

// ---------------------------------------------------------------------------
extern "C" void kernel_launch(void* const* d_in, const int* in_sizes, int n_in,
                              void* d_out, int out_size, void* d_ws, size_t ws_size,
                              hipStream_t stream)
{
    const int*   tok        = (const int*)d_in[0];
    const float* action_emb = (const float*)d_in[1];
    const float* mol_pooler = (const float*)d_in[2];
    const float* mol_W      = (const float*)d_in[3];
    const float* mol_b      = (const float*)d_in[4];
    const float* in_proj_w  = (const float*)d_in[5];
    const float* in_proj_b  = (const float*)d_in[6];
    const float* out_w      = (const float*)d_in[7];
    const float* out_b      = (const float*)d_in[8];
    const float* lin1_w     = (const float*)d_in[9];
    const float* lin1_b     = (const float*)d_in[10];
    const float* lin2_w     = (const float*)d_in[11];
    const float* lin2_b     = (const float*)d_in[12];
    const float* ln1_g      = (const float*)d_in[13];
    const float* ln1_be     = (const float*)d_in[14];
    const float* ln2_g      = (const float*)d_in[15];
    const float* ln2_be     = (const float*)d_in[16];

    // workspace layout (bf16 region first, then f32 region; all 16B aligned)
    ushort* poolerBf = (ushort*)d_ws;               // 1024*768
    ushort* molWt    = poolerBf + 786432;           // [256][768]
    ushort* inprojWt = molWt    + 196608;           // [4][768][256]
    ushort* sqWt     = inprojWt + 786432;           // [12][256][256] (out,lin1,lin2 x 4)
    ushort* qkvBf    = sqWt     + 786432;           // [8192][768]
    ushort* ctxBf    = qkvBf    + 6291456;          // [8192][256]
    ushort* t2Bf     = ctxBf    + 2097152;          // [8192][256]
    ushort* xABf     = t2Bf     + 2097152;          // [8192][256]
    ushort* xBBf     = xABf     + 2097152;          // [8192][256]
    float*  molEmb   = (float*)(xBBf + 2097152);    // [1024][256]
    float*  xA       = molEmb + 262144;             // [8192][256]
    float*  xB       = xA + 2097152;                // [8192][256]
    float*  out      = (float*)d_out;

    const dim3 blk(256);

    // weight prep (bf16 transposes)
    cvt_bf_k<<<dim3(768), blk, 0, stream>>>(mol_pooler, poolerBf);
    transpose_w_k<<<dim3(24, 8, 1),  blk, 0, stream>>>(mol_W,     molWt,    768, 256, 0, 0);
    transpose_w_k<<<dim3(8, 24, 4),  blk, 0, stream>>>(in_proj_w, inprojWt, 256, 768, 196608, 196608);
    transpose_w_k<<<dim3(8, 8, 4),   blk, 0, stream>>>(out_w,  sqWt,           256, 256, 65536, 65536);
    transpose_w_k<<<dim3(8, 8, 4),   blk, 0, stream>>>(lin1_w, sqWt + 262144,  256, 256, 65536, 65536);
    transpose_w_k<<<dim3(8, 8, 4),   blk, 0, stream>>>(lin2_w, sqWt + 524288,  256, 256, 65536, 65536);

    // mol_linear (fp32 out)
    bgemm_k<false, false, true, false><<<dim3(4, 8), blk, 0, stream>>>(
        poolerBf, molWt, mol_b, nullptr, molEmb, nullptr, 256, 768);

    // embedding
    embed_k<<<dim3(ROWS), blk, 0, stream>>>(tok, action_emb, molEmb, xA, xABf);

    for (int l = 0; l < LL; ++l) {
        // qkv = x @ wqkv + b  (bf16 out)
        bgemm_k<false, false, false, true><<<dim3(12, 64), blk, 0, stream>>>(
            xABf, inprojWt + (size_t)l * 196608, in_proj_b + (size_t)l * D3,
            nullptr, nullptr, qkvBf, D3, Dd);

        // attention
        attn_mfma_k<<<dim3(1024), blk, 0, stream>>>(qkvBf, ctxBf);

        // xA += ctx @ wo + bo (in-place residual, fp32)
        bgemm_k<false, true, true, false><<<dim3(4, 64), blk, 0, stream>>>(
            ctxBf, sqWt + (size_t)l * 65536, out_b + (size_t)l * Dd,
            xA, xA, nullptr, Dd, Dd);

        // xB = LN(xA)
        ln_k<<<dim3(ROWS / 4), blk, 0, stream>>>(xA, ln1_g + l * Dd, ln1_be + l * Dd, xB, xBBf);

        // t2 = relu(xB @ w1 + b1) (bf16 out)
        bgemm_k<true, false, false, true><<<dim3(4, 64), blk, 0, stream>>>(
            xBBf, sqWt + (size_t)(4 + l) * 65536, lin1_b + (size_t)l * Dd,
            nullptr, nullptr, t2Bf, Dd, Dd);

        // xB += t2 @ w2 + b2 (in-place residual, fp32)
        bgemm_k<false, true, true, false><<<dim3(4, 64), blk, 0, stream>>>(
            t2Bf, sqWt + (size_t)(8 + l) * 65536, lin2_b + (size_t)l * Dd,
            xB, xB, nullptr, Dd, Dd);

        // xA = LN(xB)
        ln_k<<<dim3(ROWS / 4), blk, 0, stream>>>(xB, ln2_g + l * Dd, ln2_be + l * Dd, xA, xABf);
    }

    // out[1,8,256] = mean over S
    zero_k<<<dim3(out_size / 256), blk, 0, stream>>>(out);
    mean_partial_k<<<dim3(Bb, Ss / 64), blk, 0, stream>>>(xA, out);
}